// Round 1
// baseline (1405.791 us; speedup 1.0000x reference)
//
#include <hip/hip_runtime.h>
#include <math.h>

#define NNODES 50000
#define NEDGES 500000
#define NLAYERS 8

// ---------------- graph preprocessing ----------------

__global__ void k_count(const int* __restrict__ col, int* __restrict__ counts) {
    int e = blockIdx.x * 256 + threadIdx.x;
    if (e < NEDGES) atomicAdd(&counts[col[e]], 1);
}

__global__ void k_dinv(const int* __restrict__ counts, float* __restrict__ dinv) {
    int i = blockIdx.x * 256 + threadIdx.x;
    if (i < NNODES) dinv[i] = rsqrtf((float)(counts[i] + 1));  // +1 self loop
}

__global__ __launch_bounds__(1024) void k_scan(const int* __restrict__ counts,
                                               int* __restrict__ offs) {
    __shared__ int ls[1024];
    int t = threadIdx.x;
    const int chunk = (NNODES + 1023) >> 10;  // 49
    int lo = t * chunk;
    int hi = lo + chunk; if (hi > NNODES) hi = NNODES;
    int s = 0;
    for (int i = lo; i < hi && i < NNODES; ++i) s += counts[i];
    ls[t] = s;
    __syncthreads();
    for (int off = 1; off < 1024; off <<= 1) {
        int v = (t >= off) ? ls[t - off] : 0;
        __syncthreads();
        ls[t] += v;
        __syncthreads();
    }
    int run = (t == 0) ? 0 : ls[t - 1];
    for (int i = lo; i < hi && i < NNODES; ++i) { offs[i] = run; run += counts[i]; }
    if (t == 1023) offs[NNODES] = ls[1023];
}

__global__ void k_scatter(const int* __restrict__ row, const int* __restrict__ col,
                          const int* __restrict__ offs, int* __restrict__ cursor,
                          const float* __restrict__ dinv,
                          int* __restrict__ csr_row, float* __restrict__ csr_w) {
    int e = blockIdx.x * 256 + threadIdx.x;
    if (e < NEDGES) {
        int c = col[e], r = row[e];
        int pos = offs[c] + atomicAdd(&cursor[c], 1);
        csr_row[pos] = r;
        csr_w[pos] = dinv[r] * dinv[c];
    }
}

// ---------------- folded layer weights ----------------
// Wc[i] (256x128): top = beta*w1 + (1-beta)*I ; bottom = 0.5*(beta*w2 + (1-beta)*I)
__global__ void k_wc(const float* __restrict__ w1, const float* __restrict__ w2,
                     float* __restrict__ Wc) {
    int idx = blockIdx.x * 256 + threadIdx.x;  // 8*256*128
    if (idx >= NLAYERS * 256 * 128) return;
    int i = idx >> 15;
    int rem = idx & 32767;
    int k = rem >> 7, n = rem & 127;
    float beta = logf(1.0f / (float)(i + 1) + 1.0f);
    float v;
    if (k < 128) {
        v = beta * w1[(i * 128 + k) * 128 + n] + ((k == n) ? (1.0f - beta) : 0.0f);
    } else {
        int k2 = k - 128;
        v = 0.5f * (beta * w2[(i * 128 + k2) * 128 + n] + ((k2 == n) ? (1.0f - beta) : 0.0f));
    }
    Wc[idx] = v;
}

// ---------------- lin1: h0 = x @ W(64x128) + b ; also h = h0 ----------------
__global__ __launch_bounds__(256) void k_lin1(const float* __restrict__ x,
                                              const float* __restrict__ W,
                                              const float* __restrict__ b,
                                              float* __restrict__ h0,
                                              float* __restrict__ h) {
    __shared__ float ws[64][128];
    __shared__ float xs[16][64];
    int t = threadIdx.x;
    for (int idx = t; idx < 64 * 128; idx += 256) ws[idx >> 7][idx & 127] = W[idx];
    int m0 = blockIdx.x * 16;
    for (int idx = t; idx < 16 * 64; idx += 256) {
        int r = idx >> 6, k = idx & 63;
        int m = m0 + r;
        xs[r][k] = (m < NNODES) ? x[(size_t)m * 64 + k] : 0.0f;
    }
    __syncthreads();
    int n = t & 127, rr = t >> 7;
    for (int r = rr; r < 16; r += 2) {
        int m = m0 + r;
        if (m >= NNODES) break;
        float acc = b[n];
#pragma unroll
        for (int k = 0; k < 64; ++k) acc += xs[r][k] * ws[k][n];
        h0[(size_t)m * 128 + n] = acc;
        h[(size_t)m * 128 + n] = acc;
    }
}

// ---------------- SpMM: agg = 0.5 * (A_hat @ h) ----------------
__global__ __launch_bounds__(256) void k_spmm(const float* __restrict__ h,
                                              const int* __restrict__ offs,
                                              const int* __restrict__ csr_row,
                                              const float* __restrict__ csr_w,
                                              const float* __restrict__ dinv,
                                              float* __restrict__ agg) {
    int wid = (blockIdx.x * 256 + threadIdx.x) >> 6;
    int lane = threadIdx.x & 63;
    if (wid >= NNODES) return;
    int c = wid;
    float di = dinv[c];
    float2 hc = *(const float2*)(h + (size_t)c * 128 + lane * 2);
    float acc0 = di * di * hc.x, acc1 = di * di * hc.y;
    int e0 = offs[c], e1 = offs[c + 1];
    for (int e = e0; e < e1; ++e) {
        int r = csr_row[e];
        float w = csr_w[e];
        float2 hv = *(const float2*)(h + (size_t)r * 128 + lane * 2);
        acc0 += w * hv.x;
        acc1 += w * hv.y;
    }
    float2 o;
    o.x = 0.5f * acc0;
    o.y = 0.5f * acc1;
    *(float2*)(agg + (size_t)c * 128 + lane * 2) = o;
}

// ---------------- layer GEMM: out = [agg|h0] @ Wc  + fused sum/sumsq ----------------
__global__ __launch_bounds__(256) void k_gemm_layer(const float* __restrict__ agg,
                                                    const float* __restrict__ h0,
                                                    const float* __restrict__ Wc,
                                                    float* __restrict__ outb,
                                                    float* __restrict__ stats) {
    __shared__ float As[32][68];   // [kk][m], padded
    __shared__ float Bs[32][128];  // [kk][n]
    __shared__ float red1[256];
    __shared__ float red2[256];
    int t = threadIdx.x;
    int m0 = blockIdx.x * 64;
    float acc[4][8] = {};
    int r0 = (t >> 4) << 2;   // 0..60
    int c0 = (t & 15) << 3;   // 0..120
    int kv = t & 7, am = t >> 3;   // A loader
    int bk = t >> 3, bn = t & 7;   // B loader

    for (int kt = 0; kt < 8; ++kt) {
        int k0 = kt * 32;
        const float* __restrict__ src = (k0 < 128) ? agg : h0;
        int kb = k0 & 127;
        __syncthreads();
#pragma unroll
        for (int it = 0; it < 2; ++it) {
            int m = am + it * 32;
            int gm = m0 + m;
            float4 v = make_float4(0.f, 0.f, 0.f, 0.f);
            if (gm < NNODES) v = *(const float4*)&src[(size_t)gm * 128 + kb + kv * 4];
            As[kv * 4 + 0][m] = v.x;
            As[kv * 4 + 1][m] = v.y;
            As[kv * 4 + 2][m] = v.z;
            As[kv * 4 + 3][m] = v.w;
        }
#pragma unroll
        for (int j = 0; j < 4; ++j) {
            *(float4*)&Bs[bk][4 * (bn + 8 * j)] =
                *(const float4*)&Wc[(size_t)(k0 + bk) * 128 + 4 * (bn + 8 * j)];
        }
        __syncthreads();
        for (int kk = 0; kk < 32; ++kk) {
            float4 a = *(const float4*)&As[kk][r0];
            float4 b0 = *(const float4*)&Bs[kk][c0];
            float4 b1 = *(const float4*)&Bs[kk][c0 + 4];
            float av[4] = {a.x, a.y, a.z, a.w};
            float bv[8] = {b0.x, b0.y, b0.z, b0.w, b1.x, b1.y, b1.z, b1.w};
#pragma unroll
            for (int i = 0; i < 4; ++i)
#pragma unroll
                for (int j = 0; j < 8; ++j) acc[i][j] += av[i] * bv[j];
        }
    }

    float s1 = 0.f, s2 = 0.f;
#pragma unroll
    for (int i = 0; i < 4; ++i) {
        int m = m0 + r0 + i;
        if (m < NNODES) {
            float4 o0 = make_float4(acc[i][0], acc[i][1], acc[i][2], acc[i][3]);
            float4 o1 = make_float4(acc[i][4], acc[i][5], acc[i][6], acc[i][7]);
            *(float4*)&outb[(size_t)m * 128 + c0] = o0;
            *(float4*)&outb[(size_t)m * 128 + c0 + 4] = o1;
#pragma unroll
            for (int j = 0; j < 8; ++j) { float v = acc[i][j]; s1 += v; s2 += v * v; }
        }
    }
    red1[t] = s1;
    red2[t] = s2;
    __syncthreads();
    for (int o = 128; o > 0; o >>= 1) {
        if (t < o) { red1[t] += red1[t + o]; red2[t] += red2[t + o]; }
        __syncthreads();
    }
    if (t == 0) {
        atomicAdd(stats, red1[0]);
        atomicAdd(stats + 1, red2[0]);
    }
}

// ---------------- LayerNorm(graph) + ReLU ----------------
__global__ void k_ln(const float* __restrict__ outb, const float* __restrict__ stats,
                     const float* __restrict__ nw, const float* __restrict__ nb,
                     float* __restrict__ h) {
    float S1 = stats[0], S2 = stats[1];
    const float M = (float)NNODES * 128.0f;
    float mean = S1 / M;
    float var = S2 / M - mean * mean;
    float inv = 1.0f / (sqrtf(fmaxf(var, 0.0f)) + 1e-5f);
    int total = NNODES * 32;  // float4s
    for (int idx = blockIdx.x * blockDim.x + threadIdx.x; idx < total;
         idx += gridDim.x * blockDim.x) {
        float4 v = ((const float4*)outb)[idx];
        int n = (idx & 31) * 4;
        float4 r;
        r.x = fmaxf((v.x - mean) * inv * nw[n + 0] + nb[n + 0], 0.0f);
        r.y = fmaxf((v.y - mean) * inv * nw[n + 1] + nb[n + 1], 0.0f);
        r.z = fmaxf((v.z - mean) * inv * nw[n + 2] + nb[n + 2], 0.0f);
        r.w = fmaxf((v.w - mean) * inv * nw[n + 3] + nb[n + 3], 0.0f);
        ((float4*)h)[idx] = r;
    }
}

// ---------------- lin2: out = h @ W(128x64) + b ----------------
__global__ __launch_bounds__(256) void k_lin2(const float* __restrict__ h,
                                              const float* __restrict__ W,
                                              const float* __restrict__ b,
                                              float* __restrict__ out) {
    __shared__ float ws[128][64];
    __shared__ float xs[16][128];
    int t = threadIdx.x;
    for (int idx = t; idx < 128 * 64; idx += 256) ws[idx >> 6][idx & 63] = W[idx];
    int m0 = blockIdx.x * 16;
    for (int idx = t; idx < 16 * 128; idx += 256) {
        int r = idx >> 7, k = idx & 127;
        int m = m0 + r;
        xs[r][k] = (m < NNODES) ? h[(size_t)m * 128 + k] : 0.0f;
    }
    __syncthreads();
    int n = t & 63, rr = t >> 6;
    for (int r = rr; r < 16; r += 4) {
        int m = m0 + r;
        if (m >= NNODES) break;
        float acc = b[n];
#pragma unroll
        for (int k = 0; k < 128; ++k) acc += xs[r][k] * ws[k][n];
        out[(size_t)m * 64 + n] = acc;
    }
}

// ---------------- launch ----------------

extern "C" void kernel_launch(void* const* d_in, const int* in_sizes, int n_in,
                              void* d_out, int out_size, void* d_ws, size_t ws_size,
                              hipStream_t stream) {
    const float* x      = (const float*)d_in[0];
    const int*   ei     = (const int*)d_in[1];   // (2, E) int32
    const float* lin1_w = (const float*)d_in[2];
    const float* lin1_b = (const float*)d_in[3];
    const float* w1     = (const float*)d_in[4];
    const float* w2     = (const float*)d_in[5];
    const float* norm_w = (const float*)d_in[6];
    const float* norm_b = (const float*)d_in[7];
    const float* lin2_w = (const float*)d_in[8];
    const float* lin2_b = (const float*)d_in[9];
    float* out = (float*)d_out;

    const int* row = ei;
    const int* col = ei + NEDGES;

    char* p = (char*)d_ws;
    auto take = [&](size_t bytes) -> char* {
        char* r = p;
        p += (bytes + 255) & ~(size_t)255;
        return r;
    };
    float* h0      = (float*)take((size_t)NNODES * 128 * 4);
    float* h       = (float*)take((size_t)NNODES * 128 * 4);
    float* agg     = (float*)take((size_t)NNODES * 128 * 4);
    float* outb    = (float*)take((size_t)NNODES * 128 * 4);
    float* Wc      = (float*)take((size_t)NLAYERS * 256 * 128 * 4);
    float* dinv    = (float*)take((size_t)NNODES * 4);
    int*   counts  = (int*)take((size_t)NNODES * 4);
    int*   cursor  = (int*)take((size_t)NNODES * 4);
    int*   offs    = (int*)take((size_t)(NNODES + 1) * 4);
    int*   csr_row = (int*)take((size_t)NEDGES * 4);
    float* csr_w   = (float*)take((size_t)NEDGES * 4);
    float* stats   = (float*)take(64);  // 2 floats per layer

    hipMemsetAsync(counts, 0, (size_t)NNODES * 4, stream);
    hipMemsetAsync(cursor, 0, (size_t)NNODES * 4, stream);
    hipMemsetAsync(stats, 0, 64, stream);

    k_count<<<(NEDGES + 255) / 256, 256, 0, stream>>>(col, counts);
    k_dinv<<<(NNODES + 255) / 256, 256, 0, stream>>>(counts, dinv);
    k_scan<<<1, 1024, 0, stream>>>(counts, offs);
    k_scatter<<<(NEDGES + 255) / 256, 256, 0, stream>>>(row, col, offs, cursor, dinv,
                                                        csr_row, csr_w);
    k_wc<<<(NLAYERS * 256 * 128 + 255) / 256, 256, 0, stream>>>(w1, w2, Wc);
    k_lin1<<<(NNODES + 15) / 16, 256, 0, stream>>>(x, lin1_w, lin1_b, h0, h);

    for (int i = 0; i < NLAYERS; ++i) {
        k_spmm<<<(NNODES * 64 + 255) / 256, 256, 0, stream>>>(h, offs, csr_row, csr_w,
                                                              dinv, agg);
        k_gemm_layer<<<(NNODES + 63) / 64, 256, 0, stream>>>(
            agg, h0, Wc + (size_t)i * 256 * 128, outb, stats + 2 * i);
        k_ln<<<2048, 256, 0, stream>>>(outb, stats + 2 * i, norm_w + (size_t)i * 128,
                                       norm_b + (size_t)i * 128, h);
    }
    k_lin2<<<(NNODES + 15) / 16, 256, 0, stream>>>(h, lin2_w, lin2_b, out);
}

// Round 2
// 841.846 us; speedup vs baseline: 1.6699x; 1.6699x over previous
//
#include <hip/hip_runtime.h>
#include <hip/hip_bf16.h>
#include <math.h>

#define NNODES 50000
#define NEDGES 500000
#define NLAYERS 8

typedef __attribute__((ext_vector_type(8))) short bhalf8;
typedef __attribute__((ext_vector_type(4))) float f32x4;

// fp32 -> bf16 bits, round-to-nearest-even
static __device__ __forceinline__ unsigned short f2b(float v) {
    unsigned u = __builtin_bit_cast(unsigned, v);
    u += 0x7fffu + ((u >> 16) & 1u);
    return (unsigned short)(u >> 16);
}
static __device__ __forceinline__ float b2f_lo(unsigned w) {
    return __builtin_bit_cast(float, w << 16);
}
static __device__ __forceinline__ float b2f_hi(unsigned w) {
    return __builtin_bit_cast(float, w & 0xffff0000u);
}

// ---------------- graph preprocessing ----------------

__global__ void k_count(const int* __restrict__ col, int* __restrict__ counts) {
    int e = blockIdx.x * 256 + threadIdx.x;
    if (e < NEDGES) atomicAdd(&counts[col[e]], 1);
}

__global__ void k_dinv(const int* __restrict__ counts, float* __restrict__ dinv) {
    int i = blockIdx.x * 256 + threadIdx.x;
    if (i < NNODES) dinv[i] = rsqrtf((float)(counts[i] + 1));  // +1 self loop
}

__global__ __launch_bounds__(1024) void k_scan(const int* __restrict__ counts,
                                               int* __restrict__ offs) {
    __shared__ int ls[1024];
    int t = threadIdx.x;
    const int chunk = (NNODES + 1023) >> 10;  // 49
    int lo = t * chunk;
    int hi = lo + chunk; if (hi > NNODES) hi = NNODES;
    int s = 0;
    for (int i = lo; i < hi && i < NNODES; ++i) s += counts[i];
    ls[t] = s;
    __syncthreads();
    for (int off = 1; off < 1024; off <<= 1) {
        int v = (t >= off) ? ls[t - off] : 0;
        __syncthreads();
        ls[t] += v;
        __syncthreads();
    }
    int run = (t == 0) ? 0 : ls[t - 1];
    for (int i = lo; i < hi && i < NNODES; ++i) { offs[i] = run; run += counts[i]; }
    if (t == 1023) offs[NNODES] = ls[1023];
}

__global__ void k_scatter(const int* __restrict__ row, const int* __restrict__ col,
                          const int* __restrict__ offs, int* __restrict__ cursor,
                          const float* __restrict__ dinv,
                          int* __restrict__ csr_row, float* __restrict__ csr_w) {
    int e = blockIdx.x * 256 + threadIdx.x;
    if (e < NEDGES) {
        int c = col[e], r = row[e];
        int pos = offs[c] + atomicAdd(&cursor[c], 1);
        csr_row[pos] = r;
        csr_w[pos] = dinv[r] * dinv[c];
    }
}

// ---------------- folded + MFMA-fragment-packed layer weights ----------------
// Logical Wc[i] (256x128): top = beta*w1 + (1-beta)*I ; bottom = 0.5*(beta*w2 + (1-beta)*I)
// Packed as bf16: idx = ((i*8+s)*8+t)*512 + lane*8 + j
//   maps to  k = s*32 + (lane>>4)*8 + j,  n = t*16 + (lane&15)
__global__ void k_wcp(const float* __restrict__ w1, const float* __restrict__ w2,
                      unsigned short* __restrict__ Wp) {
    int idx = blockIdx.x * 256 + threadIdx.x;  // 8*32768
    if (idx >= NLAYERS * 32768) return;
    int i = idx >> 15;
    int rem = idx & 32767;
    int s = rem >> 12;
    int t = (rem >> 9) & 7;
    int lane = (rem >> 3) & 63;
    int j = rem & 7;
    int k = s * 32 + (lane >> 4) * 8 + j;
    int n = t * 16 + (lane & 15);
    float beta = logf(1.0f / (float)(i + 1) + 1.0f);
    float v;
    if (k < 128) {
        v = beta * w1[(i * 128 + k) * 128 + n] + ((k == n) ? (1.0f - beta) : 0.0f);
    } else {
        int k2 = k - 128;
        v = 0.5f * (beta * w2[(i * 128 + k2) * 128 + n] + ((k2 == n) ? (1.0f - beta) : 0.0f));
    }
    Wp[idx] = f2b(v);
}

// ---------------- lin1: h0 = x @ W(64x128) + b -> bf16 into abuf[:,128:256) ----------------
__global__ __launch_bounds__(256) void k_lin1(const float* __restrict__ x,
                                              const float* __restrict__ W,
                                              const float* __restrict__ b,
                                              unsigned short* __restrict__ abuf) {
    __shared__ float ws[64][128];
    __shared__ float xs[16][64];
    int t = threadIdx.x;
    for (int idx = t; idx < 64 * 128; idx += 256) ws[idx >> 7][idx & 127] = W[idx];
    int m0 = blockIdx.x * 16;
    for (int idx = t; idx < 16 * 64; idx += 256) {
        int r = idx >> 6, k = idx & 63;
        int m = m0 + r;
        xs[r][k] = (m < NNODES) ? x[(size_t)m * 64 + k] : 0.0f;
    }
    __syncthreads();
    int n = t & 127, rr = t >> 7;
    for (int r = rr; r < 16; r += 2) {
        int m = m0 + r;
        if (m >= NNODES) break;
        float acc = b[n];
#pragma unroll
        for (int k = 0; k < 64; ++k) acc += xs[r][k] * ws[k][n];
        abuf[(size_t)m * 256 + 128 + n] = f2b(acc);
    }
}

// ---------------- SpMM with fused LayerNorm+ReLU of the source ----------------
// agg(=abuf[:,0:128)) = 0.5 * A_hat @ f(src) ;  f = LN+relu (or identity for layer 0)
__global__ __launch_bounds__(256) void k_spmm2(const unsigned short* __restrict__ src,
                                               int stride, int apply_ln,
                                               const float* __restrict__ stats,
                                               const float* __restrict__ nw,
                                               const float* __restrict__ nb,
                                               const int* __restrict__ offs,
                                               const int* __restrict__ csr_row,
                                               const float* __restrict__ csr_w,
                                               const float* __restrict__ dinv,
                                               unsigned short* __restrict__ abuf) {
    int wid = (blockIdx.x * 256 + threadIdx.x) >> 6;
    int lane = threadIdx.x & 63;
    if (wid >= NNODES) return;
    float s0 = 1.0f, c0 = 0.0f, s1 = 1.0f, c1 = 0.0f;
    if (apply_ln) {
        const float M = (float)NNODES * 128.0f;
        float mean = stats[0] / M;
        float var = stats[1] / M - mean * mean;
        float inv = 1.0f / (sqrtf(fmaxf(var, 0.0f)) + 1e-5f);
        float w0 = nw[lane * 2], w1 = nw[lane * 2 + 1];
        s0 = inv * w0; c0 = nb[lane * 2] - mean * s0;
        s1 = inv * w1; c1 = nb[lane * 2 + 1] - mean * s1;
    }
    int c = wid;
    float di = dinv[c];
    float dw = di * di;
    unsigned hv = *(const unsigned*)(src + (size_t)c * stride + lane * 2);
    float v0 = fmaf(b2f_lo(hv), s0, c0), v1 = fmaf(b2f_hi(hv), s1, c1);
    if (apply_ln) { v0 = fmaxf(v0, 0.0f); v1 = fmaxf(v1, 0.0f); }
    float acc0 = dw * v0, acc1 = dw * v1;
    int e = offs[c], e1 = offs[c + 1];
    for (; e + 1 < e1; e += 2) {
        int r0 = csr_row[e], r1 = csr_row[e + 1];
        float we0 = csr_w[e], we1 = csr_w[e + 1];
        unsigned a0 = *(const unsigned*)(src + (size_t)r0 * stride + lane * 2);
        unsigned a1 = *(const unsigned*)(src + (size_t)r1 * stride + lane * 2);
        float p0 = fmaf(b2f_lo(a0), s0, c0), p1 = fmaf(b2f_hi(a0), s1, c1);
        float q0 = fmaf(b2f_lo(a1), s0, c0), q1 = fmaf(b2f_hi(a1), s1, c1);
        if (apply_ln) {
            p0 = fmaxf(p0, 0.0f); p1 = fmaxf(p1, 0.0f);
            q0 = fmaxf(q0, 0.0f); q1 = fmaxf(q1, 0.0f);
        }
        acc0 = fmaf(we0, p0, acc0); acc1 = fmaf(we0, p1, acc1);
        acc0 = fmaf(we1, q0, acc0); acc1 = fmaf(we1, q1, acc1);
    }
    if (e < e1) {
        int r0 = csr_row[e];
        float we0 = csr_w[e];
        unsigned a0 = *(const unsigned*)(src + (size_t)r0 * stride + lane * 2);
        float p0 = fmaf(b2f_lo(a0), s0, c0), p1 = fmaf(b2f_hi(a0), s1, c1);
        if (apply_ln) { p0 = fmaxf(p0, 0.0f); p1 = fmaxf(p1, 0.0f); }
        acc0 = fmaf(we0, p0, acc0); acc1 = fmaf(we0, p1, acc1);
    }
    unsigned out = (unsigned)f2b(0.5f * acc0) | ((unsigned)f2b(0.5f * acc1) << 16);
    *(unsigned*)(abuf + (size_t)c * 256 + lane * 2) = out;
}

// ---------------- layer GEMM (MFMA): outb = abuf(50000x256 bf16) @ Wc + stats ----------------
// grid = 782 blocks, 256 threads (4 waves), tile M=64 (16 rows/wave), N=128, K=256
__global__ __launch_bounds__(256) void k_gemm2(const unsigned short* __restrict__ A,
                                               const unsigned short* __restrict__ Bp,
                                               unsigned short* __restrict__ outb,
                                               float* __restrict__ stats) {
    __shared__ __attribute__((aligned(16))) unsigned short Bs[32768];  // 64 KB
    int t = threadIdx.x;
#pragma unroll
    for (int it = 0; it < 16; ++it) {
        int o = it * 2048 + t * 8;
        *(bhalf8*)&Bs[o] = *(const bhalf8*)&Bp[o];
    }
    __syncthreads();

    int w = t >> 6, lane = t & 63;
    int q = lane >> 4, r = lane & 15;
    int m0 = blockIdx.x * 64 + w * 16;
    int mA = m0 + r; if (mA > NNODES - 1) mA = NNODES - 1;
    const unsigned short* arow = A + (size_t)mA * 256;

    f32x4 acc[8];
#pragma unroll
    for (int i = 0; i < 8; ++i) acc[i] = (f32x4){0.f, 0.f, 0.f, 0.f};

    bhalf8 afr[8];
#pragma unroll
    for (int s = 0; s < 8; ++s)
        afr[s] = *(const bhalf8*)(arow + s * 32 + q * 8);
#pragma unroll
    for (int s = 0; s < 8; ++s) {
#pragma unroll
        for (int nt = 0; nt < 8; ++nt) {
            bhalf8 bfr = *(const bhalf8*)&Bs[((s * 8 + nt) << 9) + lane * 8];
            acc[nt] = __builtin_amdgcn_mfma_f32_16x16x32_bf16(afr[s], bfr, acc[nt], 0, 0, 0);
        }
    }

    float ps1 = 0.f, ps2 = 0.f;
#pragma unroll
    for (int i = 0; i < 4; ++i) {
        int mm = m0 + q * 4 + i;
        if (mm < NNODES) {
#pragma unroll
            for (int nt = 0; nt < 8; ++nt) {
                float v = acc[nt][i];
                ps1 += v; ps2 += v * v;
                outb[(size_t)mm * 128 + nt * 16 + r] = f2b(v);
            }
        }
    }
    __syncthreads();
    float* red = (float*)Bs;
    red[t] = ps1; red[256 + t] = ps2;
    __syncthreads();
    for (int o = 128; o > 0; o >>= 1) {
        if (t < o) { red[t] += red[t + o]; red[256 + t] += red[256 + t + o]; }
        __syncthreads();
    }
    if (t == 0) {
        atomicAdd(stats, red[0]);
        atomicAdd(stats + 1, red[256]);
    }
}

// ---------------- lin2 with fused final LayerNorm+ReLU ----------------
__global__ __launch_bounds__(256) void k_lin2f(const unsigned short* __restrict__ hsrc,
                                               const float* __restrict__ stats,
                                               const float* __restrict__ nw,
                                               const float* __restrict__ nb,
                                               const float* __restrict__ W,
                                               const float* __restrict__ b,
                                               float* __restrict__ out) {
    __shared__ float ws[128][64];
    __shared__ float xs[16][128];
    int t = threadIdx.x;
    const float M = (float)NNODES * 128.0f;
    float mean = stats[0] / M;
    float var = stats[1] / M - mean * mean;
    float inv = 1.0f / (sqrtf(fmaxf(var, 0.0f)) + 1e-5f);
    for (int idx = t; idx < 128 * 64; idx += 256) ws[idx >> 6][idx & 63] = W[idx];
    int m0 = blockIdx.x * 16;
    for (int idx = t; idx < 16 * 128; idx += 256) {
        int r = idx >> 7, k = idx & 127;
        int m = m0 + r;
        float v = 0.0f;
        if (m < NNODES) {
            float raw = b2f_lo((unsigned)hsrc[(size_t)m * 128 + k]);
            v = fmaxf((raw - mean) * inv * nw[k] + nb[k], 0.0f);
        }
        xs[r][k] = v;
    }
    __syncthreads();
    int n = t & 63, rr = t >> 6;
    for (int r = rr; r < 16; r += 4) {
        int m = m0 + r;
        if (m >= NNODES) break;
        float acc = b[n];
#pragma unroll
        for (int k = 0; k < 128; ++k) acc += xs[r][k] * ws[k][n];
        out[(size_t)m * 64 + n] = acc;
    }
}

// ---------------- launch ----------------

extern "C" void kernel_launch(void* const* d_in, const int* in_sizes, int n_in,
                              void* d_out, int out_size, void* d_ws, size_t ws_size,
                              hipStream_t stream) {
    const float* x      = (const float*)d_in[0];
    const int*   ei     = (const int*)d_in[1];
    const float* lin1_w = (const float*)d_in[2];
    const float* lin1_b = (const float*)d_in[3];
    const float* w1     = (const float*)d_in[4];
    const float* w2     = (const float*)d_in[5];
    const float* norm_w = (const float*)d_in[6];
    const float* norm_b = (const float*)d_in[7];
    const float* lin2_w = (const float*)d_in[8];
    const float* lin2_b = (const float*)d_in[9];
    float* out = (float*)d_out;

    const int* row = ei;
    const int* col = ei + NEDGES;

    char* p = (char*)d_ws;
    auto take = [&](size_t bytes) -> char* {
        char* r = p;
        p += (bytes + 255) & ~(size_t)255;
        return r;
    };
    unsigned short* abuf = (unsigned short*)take((size_t)NNODES * 256 * 2);  // [agg | h0] bf16
    unsigned short* outb = (unsigned short*)take((size_t)NNODES * 128 * 2);  // layer out bf16
    unsigned short* Wp   = (unsigned short*)take((size_t)NLAYERS * 32768 * 2);
    float* dinv    = (float*)take((size_t)NNODES * 4);
    int*   counts  = (int*)take((size_t)NNODES * 4);
    int*   cursor  = (int*)take((size_t)NNODES * 4);
    int*   offs    = (int*)take((size_t)(NNODES + 1) * 4);
    int*   csr_row = (int*)take((size_t)NEDGES * 4);
    float* csr_w   = (float*)take((size_t)NEDGES * 4);
    float* stats   = (float*)take(64);  // 2 floats per layer

    hipMemsetAsync(counts, 0, (size_t)NNODES * 4, stream);
    hipMemsetAsync(cursor, 0, (size_t)NNODES * 4, stream);
    hipMemsetAsync(stats, 0, 64, stream);

    k_count<<<(NEDGES + 255) / 256, 256, 0, stream>>>(col, counts);
    k_dinv<<<(NNODES + 255) / 256, 256, 0, stream>>>(counts, dinv);
    k_scan<<<1, 1024, 0, stream>>>(counts, offs);
    k_scatter<<<(NEDGES + 255) / 256, 256, 0, stream>>>(row, col, offs, cursor, dinv,
                                                        csr_row, csr_w);
    k_wcp<<<(NLAYERS * 32768 + 255) / 256, 256, 0, stream>>>(w1, w2, Wp);
    k_lin1<<<(NNODES + 15) / 16, 256, 0, stream>>>(x, lin1_w, lin1_b, abuf);

    for (int i = 0; i < NLAYERS; ++i) {
        const unsigned short* src = (i == 0) ? (abuf + 128) : outb;
        int stride = (i == 0) ? 256 : 128;
        k_spmm2<<<(NNODES * 64 + 255) / 256, 256, 0, stream>>>(
            src, stride, (i == 0) ? 0 : 1, stats + 2 * (i - 1),
            norm_w + (size_t)(i > 0 ? i - 1 : 0) * 128,
            norm_b + (size_t)(i > 0 ? i - 1 : 0) * 128,
            offs, csr_row, csr_w, dinv, abuf);
        k_gemm2<<<(NNODES + 63) / 64, 256, 0, stream>>>(abuf, Wp + (size_t)i * 32768,
                                                        outb, stats + 2 * i);
    }
    k_lin2f<<<(NNODES + 15) / 16, 256, 0, stream>>>(outb, stats + 14,
                                                    norm_w + 7 * 128, norm_b + 7 * 128,
                                                    lin2_w, lin2_b, out);
}

// Round 3
// 691.249 us; speedup vs baseline: 2.0337x; 1.2179x over previous
//
#include <hip/hip_runtime.h>
#include <hip/hip_bf16.h>
#include <math.h>

#define NNODES 50000
#define NEDGES 500000
#define NLAYERS 8
#define NSCANB 196  // ceil(NNODES/256)

typedef __attribute__((ext_vector_type(8))) short bhalf8;
typedef __attribute__((ext_vector_type(4))) float f32x4;

// fp32 -> bf16 bits, round-to-nearest-even
static __device__ __forceinline__ unsigned short f2b(float v) {
    unsigned u = __builtin_bit_cast(unsigned, v);
    u += 0x7fffu + ((u >> 16) & 1u);
    return (unsigned short)(u >> 16);
}
static __device__ __forceinline__ float b2f_lo(unsigned w) {
    return __builtin_bit_cast(float, w << 16);
}
static __device__ __forceinline__ float b2f_hi(unsigned w) {
    return __builtin_bit_cast(float, w & 0xffff0000u);
}

// ---------------- graph preprocessing ----------------

__global__ void k_count(const int* __restrict__ col, int* __restrict__ counts) {
    int e = blockIdx.x * 256 + threadIdx.x;
    if (e < NEDGES) atomicAdd(&counts[col[e]], 1);
}

__global__ void k_dinv(const int* __restrict__ counts, float* __restrict__ dinv) {
    int i = blockIdx.x * 256 + threadIdx.x;
    if (i < NNODES) dinv[i] = rsqrtf((float)(counts[i] + 1));  // +1 self loop
}

// parallel scan, 3 stages
__global__ __launch_bounds__(256) void k_bsum(const int* __restrict__ counts,
                                              int* __restrict__ part) {
    __shared__ int ls[256];
    int t = threadIdx.x, i = blockIdx.x * 256 + t;
    ls[t] = (i < NNODES) ? counts[i] : 0;
    __syncthreads();
    for (int o = 128; o > 0; o >>= 1) {
        if (t < o) ls[t] += ls[t + o];
        __syncthreads();
    }
    if (t == 0) part[blockIdx.x] = ls[0];
}

__global__ __launch_bounds__(256) void k_pscan(int* __restrict__ part) {
    __shared__ int ls[256];
    int t = threadIdx.x;
    int v = (t < NSCANB) ? part[t] : 0;
    ls[t] = v;
    __syncthreads();
    for (int o = 1; o < 256; o <<= 1) {
        int x = (t >= o) ? ls[t - o] : 0;
        __syncthreads();
        ls[t] += x;
        __syncthreads();
    }
    if (t < NSCANB) part[t] = ls[t] - v;  // exclusive
}

__global__ __launch_bounds__(256) void k_offs(const int* __restrict__ counts,
                                              const int* __restrict__ part,
                                              int* __restrict__ offs) {
    __shared__ int ls[256];
    int t = threadIdx.x, i = blockIdx.x * 256 + t;
    int v = (i < NNODES) ? counts[i] : 0;
    ls[t] = v;
    __syncthreads();
    for (int o = 1; o < 256; o <<= 1) {
        int x = (t >= o) ? ls[t - o] : 0;
        __syncthreads();
        ls[t] += x;
        __syncthreads();
    }
    int excl = part[blockIdx.x] + ls[t] - v;
    if (i < NNODES) offs[i] = excl;
    if (i == NNODES - 1) offs[NNODES] = excl + v;
}

__global__ void k_scatter(const int* __restrict__ row, const int* __restrict__ col,
                          const int* __restrict__ offs, int* __restrict__ cursor,
                          const float* __restrict__ dinv, int2* __restrict__ csr) {
    int e = blockIdx.x * 256 + threadIdx.x;
    if (e < NEDGES) {
        int c = col[e], r = row[e];
        int pos = offs[c] + atomicAdd(&cursor[c], 1);
        float w = dinv[r] * dinv[c];
        csr[pos] = make_int2(r, __builtin_bit_cast(int, w));
    }
}

// ---------------- folded + MFMA-fragment-packed layer weights ----------------
__global__ void k_wcp(const float* __restrict__ w1, const float* __restrict__ w2,
                      unsigned short* __restrict__ Wp) {
    int idx = blockIdx.x * 256 + threadIdx.x;  // 8*32768
    if (idx >= NLAYERS * 32768) return;
    int i = idx >> 15;
    int rem = idx & 32767;
    int s = rem >> 12;
    int t = (rem >> 9) & 7;
    int lane = (rem >> 3) & 63;
    int j = rem & 7;
    int k = s * 32 + (lane >> 4) * 8 + j;
    int n = t * 16 + (lane & 15);
    float beta = logf(1.0f / (float)(i + 1) + 1.0f);
    float v;
    if (k < 128) {
        v = beta * w1[(i * 128 + k) * 128 + n] + ((k == n) ? (1.0f - beta) : 0.0f);
    } else {
        int k2 = k - 128;
        v = 0.5f * (beta * w2[(i * 128 + k2) * 128 + n] + ((k2 == n) ? (1.0f - beta) : 0.0f));
    }
    Wp[idx] = f2b(v);
}

// ---------------- lin1: h0 = x @ W(64x128) + b -> bf16 into abuf[:,128:256) ----------------
__global__ __launch_bounds__(256) void k_lin1(const float* __restrict__ x,
                                              const float* __restrict__ W,
                                              const float* __restrict__ b,
                                              unsigned short* __restrict__ abuf) {
    __shared__ float ws[64][128];
    __shared__ float xs[16][64];
    int t = threadIdx.x;
    for (int idx = t; idx < 64 * 128; idx += 256) ws[idx >> 7][idx & 127] = W[idx];
    int m0 = blockIdx.x * 16;
    for (int idx = t; idx < 16 * 64; idx += 256) {
        int r = idx >> 6, k = idx & 63;
        int m = m0 + r;
        xs[r][k] = (m < NNODES) ? x[(size_t)m * 64 + k] : 0.0f;
    }
    __syncthreads();
    int n = t & 127, rr = t >> 7;
    for (int r = rr; r < 16; r += 2) {
        int m = m0 + r;
        if (m >= NNODES) break;
        float acc = b[n];
#pragma unroll
        for (int k = 0; k < 64; ++k) acc += xs[r][k] * ws[k][n];
        abuf[(size_t)m * 256 + 128 + n] = f2b(acc);
    }
}

// ---------------- SpMM with fused LayerNorm+ReLU of the source ----------------
template <int LN>
static __device__ __forceinline__ void acc_edge(unsigned a, float we, float s0, float c0,
                                                float s1, float c1,
                                                float& acc0, float& acc1) {
    float p0 = fmaf(b2f_lo(a), s0, c0);
    float p1 = fmaf(b2f_hi(a), s1, c1);
    if (LN) { p0 = fmaxf(p0, 0.0f); p1 = fmaxf(p1, 0.0f); }
    acc0 = fmaf(we, p0, acc0);
    acc1 = fmaf(we, p1, acc1);
}

template <int LN>
__global__ __launch_bounds__(256) void k_spmm3(const unsigned short* __restrict__ src,
                                               int stride,
                                               const float* __restrict__ stats,
                                               const float* __restrict__ nw,
                                               const float* __restrict__ nb,
                                               const int* __restrict__ offs,
                                               const int2* __restrict__ csr,
                                               const float* __restrict__ dinv,
                                               unsigned short* __restrict__ abuf) {
    int wid = (blockIdx.x * 256 + threadIdx.x) >> 6;
    int lane = threadIdx.x & 63;
    if (wid >= NNODES) return;
    float s0 = 1.0f, c0 = 0.0f, s1 = 1.0f, c1 = 0.0f;
    if (LN) {
        const float M = (float)NNODES * 128.0f;
        float mean = stats[0] / M;
        float var = stats[1] / M - mean * mean;
        float inv = 1.0f / (sqrtf(fmaxf(var, 0.0f)) + 1e-5f);
        s0 = inv * nw[lane * 2];
        c0 = nb[lane * 2] - mean * s0;
        s1 = inv * nw[lane * 2 + 1];
        c1 = nb[lane * 2 + 1] - mean * s1;
    }
    int c = wid;
    float di = dinv[c];
    float dw = di * di;
    unsigned hv = *(const unsigned*)(src + (size_t)c * stride + lane * 2);
    float v0 = fmaf(b2f_lo(hv), s0, c0), v1 = fmaf(b2f_hi(hv), s1, c1);
    if (LN) { v0 = fmaxf(v0, 0.0f); v1 = fmaxf(v1, 0.0f); }
    float acc0 = dw * v0, acc1 = dw * v1;
    int e = offs[c], e1 = offs[c + 1];
    for (; e + 4 <= e1; e += 4) {
        int2 E0 = csr[e], E1 = csr[e + 1], E2 = csr[e + 2], E3 = csr[e + 3];
        unsigned a0 = *(const unsigned*)(src + (size_t)E0.x * stride + lane * 2);
        unsigned a1 = *(const unsigned*)(src + (size_t)E1.x * stride + lane * 2);
        unsigned a2 = *(const unsigned*)(src + (size_t)E2.x * stride + lane * 2);
        unsigned a3 = *(const unsigned*)(src + (size_t)E3.x * stride + lane * 2);
        acc_edge<LN>(a0, __builtin_bit_cast(float, E0.y), s0, c0, s1, c1, acc0, acc1);
        acc_edge<LN>(a1, __builtin_bit_cast(float, E1.y), s0, c0, s1, c1, acc0, acc1);
        acc_edge<LN>(a2, __builtin_bit_cast(float, E2.y), s0, c0, s1, c1, acc0, acc1);
        acc_edge<LN>(a3, __builtin_bit_cast(float, E3.y), s0, c0, s1, c1, acc0, acc1);
    }
    for (; e < e1; ++e) {
        int2 E0 = csr[e];
        unsigned a0 = *(const unsigned*)(src + (size_t)E0.x * stride + lane * 2);
        acc_edge<LN>(a0, __builtin_bit_cast(float, E0.y), s0, c0, s1, c1, acc0, acc1);
    }
    unsigned out = (unsigned)f2b(0.5f * acc0) | ((unsigned)f2b(0.5f * acc1) << 16);
    *(unsigned*)(abuf + (size_t)c * 256 + lane * 2) = out;
}

// ---------------- layer GEMM (MFMA): outb = abuf(50000x256 bf16) @ Wc + stats ----------------
// grid = 391 blocks, 256 threads (4 waves); M=128 per block as 2 sub-tiles of 64,
// reusing the 64 KB LDS-resident packed B.
__global__ __launch_bounds__(256) void k_gemm2(const unsigned short* __restrict__ A,
                                               const unsigned short* __restrict__ Bp,
                                               unsigned short* __restrict__ outb,
                                               float* __restrict__ stats) {
    __shared__ __attribute__((aligned(16))) unsigned short Bs[32768];  // 64 KB
    int t = threadIdx.x;
#pragma unroll
    for (int it = 0; it < 16; ++it) {
        int o = it * 2048 + t * 8;
        *(bhalf8*)&Bs[o] = *(const bhalf8*)&Bp[o];
    }
    __syncthreads();

    int w = t >> 6, lane = t & 63;
    int q = lane >> 4, r = lane & 15;
    float ps1 = 0.f, ps2 = 0.f;

#pragma unroll 1
    for (int sub = 0; sub < 2; ++sub) {
        int m0 = blockIdx.x * 128 + sub * 64 + w * 16;
        int mA = m0 + r; if (mA > NNODES - 1) mA = NNODES - 1;
        const unsigned short* arow = A + (size_t)mA * 256;

        f32x4 acc[8];
#pragma unroll
        for (int i = 0; i < 8; ++i) acc[i] = (f32x4){0.f, 0.f, 0.f, 0.f};

        bhalf8 afr[8];
#pragma unroll
        for (int s = 0; s < 8; ++s)
            afr[s] = *(const bhalf8*)(arow + s * 32 + q * 8);
#pragma unroll
        for (int s = 0; s < 8; ++s) {
#pragma unroll
            for (int nt = 0; nt < 8; ++nt) {
                bhalf8 bfr = *(const bhalf8*)&Bs[((s * 8 + nt) << 9) + lane * 8];
                acc[nt] = __builtin_amdgcn_mfma_f32_16x16x32_bf16(afr[s], bfr, acc[nt], 0, 0, 0);
            }
        }
#pragma unroll
        for (int i = 0; i < 4; ++i) {
            int mm = m0 + q * 4 + i;
            if (mm < NNODES) {
#pragma unroll
                for (int nt = 0; nt < 8; ++nt) {
                    float v = acc[nt][i];
                    ps1 += v; ps2 += v * v;
                    outb[(size_t)mm * 128 + nt * 16 + r] = f2b(v);
                }
            }
        }
    }
    __syncthreads();
    float* red = (float*)Bs;
    red[t] = ps1; red[256 + t] = ps2;
    __syncthreads();
    for (int o = 128; o > 0; o >>= 1) {
        if (t < o) { red[t] += red[t + o]; red[256 + t] += red[256 + t + o]; }
        __syncthreads();
    }
    if (t == 0) {
        atomicAdd(stats, red[0]);
        atomicAdd(stats + 1, red[256]);
    }
}

// ---------------- lin2 with fused final LayerNorm+ReLU ----------------
__global__ __launch_bounds__(256) void k_lin2f(const unsigned short* __restrict__ hsrc,
                                               const float* __restrict__ stats,
                                               const float* __restrict__ nw,
                                               const float* __restrict__ nb,
                                               const float* __restrict__ W,
                                               const float* __restrict__ b,
                                               float* __restrict__ out) {
    __shared__ float ws[128][64];
    __shared__ float xs[16][128];
    int t = threadIdx.x;
    const float M = (float)NNODES * 128.0f;
    float mean = stats[0] / M;
    float var = stats[1] / M - mean * mean;
    float inv = 1.0f / (sqrtf(fmaxf(var, 0.0f)) + 1e-5f);
    for (int idx = t; idx < 128 * 64; idx += 256) ws[idx >> 6][idx & 63] = W[idx];
    int m0 = blockIdx.x * 16;
    for (int idx = t; idx < 16 * 128; idx += 256) {
        int r = idx >> 7, k = idx & 127;
        int m = m0 + r;
        float v = 0.0f;
        if (m < NNODES) {
            float raw = b2f_lo((unsigned)hsrc[(size_t)m * 128 + k]);
            v = fmaxf((raw - mean) * inv * nw[k] + nb[k], 0.0f);
        }
        xs[r][k] = v;
    }
    __syncthreads();
    int n = t & 63, rr = t >> 6;
    for (int r = rr; r < 16; r += 4) {
        int m = m0 + r;
        if (m >= NNODES) break;
        float acc = b[n];
#pragma unroll
        for (int k = 0; k < 128; ++k) acc += xs[r][k] * ws[k][n];
        out[(size_t)m * 64 + n] = acc;
    }
}

// ---------------- launch ----------------

extern "C" void kernel_launch(void* const* d_in, const int* in_sizes, int n_in,
                              void* d_out, int out_size, void* d_ws, size_t ws_size,
                              hipStream_t stream) {
    const float* x      = (const float*)d_in[0];
    const int*   ei     = (const int*)d_in[1];
    const float* lin1_w = (const float*)d_in[2];
    const float* lin1_b = (const float*)d_in[3];
    const float* w1     = (const float*)d_in[4];
    const float* w2     = (const float*)d_in[5];
    const float* norm_w = (const float*)d_in[6];
    const float* norm_b = (const float*)d_in[7];
    const float* lin2_w = (const float*)d_in[8];
    const float* lin2_b = (const float*)d_in[9];
    float* out = (float*)d_out;

    const int* row = ei;
    const int* col = ei + NEDGES;

    char* p = (char*)d_ws;
    auto take = [&](size_t bytes) -> char* {
        char* r = p;
        p += (bytes + 255) & ~(size_t)255;
        return r;
    };
    unsigned short* abuf = (unsigned short*)take((size_t)NNODES * 256 * 2);  // [agg | h0] bf16
    unsigned short* outb = (unsigned short*)take((size_t)NNODES * 128 * 2);  // layer out bf16
    unsigned short* Wp   = (unsigned short*)take((size_t)NLAYERS * 32768 * 2);
    float* dinv    = (float*)take((size_t)NNODES * 4);
    int*   counts  = (int*)take((size_t)NNODES * 4);
    int*   cursor  = (int*)take((size_t)NNODES * 4);
    int*   offs    = (int*)take((size_t)(NNODES + 1) * 4);
    int*   part    = (int*)take((size_t)NSCANB * 4);
    int2*  csr     = (int2*)take((size_t)NEDGES * 8);
    float* stats   = (float*)take(64);  // 2 floats per layer

    hipMemsetAsync(counts, 0, (size_t)NNODES * 4, stream);
    hipMemsetAsync(cursor, 0, (size_t)NNODES * 4, stream);
    hipMemsetAsync(stats, 0, 64, stream);

    k_count<<<(NEDGES + 255) / 256, 256, 0, stream>>>(col, counts);
    k_dinv<<<(NNODES + 255) / 256, 256, 0, stream>>>(counts, dinv);
    k_bsum<<<NSCANB, 256, 0, stream>>>(counts, part);
    k_pscan<<<1, 256, 0, stream>>>(part);
    k_offs<<<NSCANB, 256, 0, stream>>>(counts, part, offs);
    k_scatter<<<(NEDGES + 255) / 256, 256, 0, stream>>>(row, col, offs, cursor, dinv, csr);
    k_wcp<<<(NLAYERS * 32768 + 255) / 256, 256, 0, stream>>>(w1, w2, Wp);
    k_lin1<<<(NNODES + 15) / 16, 256, 0, stream>>>(x, lin1_w, lin1_b, abuf);

    for (int i = 0; i < NLAYERS; ++i) {
        if (i == 0) {
            k_spmm3<0><<<(NNODES * 64 + 255) / 256, 256, 0, stream>>>(
                abuf + 128, 256, stats, norm_w, norm_b, offs, csr, dinv, abuf);
        } else {
            k_spmm3<1><<<(NNODES * 64 + 255) / 256, 256, 0, stream>>>(
                outb, 128, stats + 2 * (i - 1), norm_w + (size_t)(i - 1) * 128,
                norm_b + (size_t)(i - 1) * 128, offs, csr, dinv, abuf);
        }
        k_gemm2<<<(NNODES + 127) / 128, 256, 0, stream>>>(abuf, Wp + (size_t)i * 32768,
                                                          outb, stats + 2 * i);
    }
    k_lin2f<<<(NNODES + 15) / 16, 256, 0, stream>>>(outb, stats + 14,
                                                    norm_w + 7 * 128, norm_b + 7 * 128,
                                                    lin2_w, lin2_b, out);
}

// Round 4
// 607.271 us; speedup vs baseline: 2.3149x; 1.1383x over previous
//
#include <hip/hip_runtime.h>
#include <hip/hip_bf16.h>
#include <math.h>

#define NNODES 50000
#define NEDGES 500000
#define NLAYERS 8
#define NSCANB 196  // ceil(NNODES/256)

typedef __attribute__((ext_vector_type(8))) short bhalf8;
typedef __attribute__((ext_vector_type(4))) float f32x4;

// fp32 -> bf16 bits, round-to-nearest-even
static __device__ __forceinline__ unsigned short f2b(float v) {
    unsigned u = __builtin_bit_cast(unsigned, v);
    u += 0x7fffu + ((u >> 16) & 1u);
    return (unsigned short)(u >> 16);
}
static __device__ __forceinline__ float b2f(unsigned short w) {
    return __builtin_bit_cast(float, (unsigned)w << 16);
}
static __device__ __forceinline__ float b2f_lo(unsigned w) {
    return __builtin_bit_cast(float, w << 16);
}
static __device__ __forceinline__ float b2f_hi(unsigned w) {
    return __builtin_bit_cast(float, w & 0xffff0000u);
}

// ---------------- graph preprocessing ----------------

__global__ void k_count(const int* __restrict__ col, int* __restrict__ counts) {
    int e = blockIdx.x * 256 + threadIdx.x;
    if (e < NEDGES) atomicAdd(&counts[col[e]], 1);
}

__global__ void k_dinv(const int* __restrict__ counts, float* __restrict__ dinv) {
    int i = blockIdx.x * 256 + threadIdx.x;
    if (i < NNODES) dinv[i] = rsqrtf((float)(counts[i] + 1));  // +1 self loop
}

__global__ __launch_bounds__(256) void k_bsum(const int* __restrict__ counts,
                                              int* __restrict__ part) {
    __shared__ int ls[256];
    int t = threadIdx.x, i = blockIdx.x * 256 + t;
    ls[t] = (i < NNODES) ? counts[i] : 0;
    __syncthreads();
    for (int o = 128; o > 0; o >>= 1) {
        if (t < o) ls[t] += ls[t + o];
        __syncthreads();
    }
    if (t == 0) part[blockIdx.x] = ls[0];
}

__global__ __launch_bounds__(256) void k_pscan(int* __restrict__ part) {
    __shared__ int ls[256];
    int t = threadIdx.x;
    int v = (t < NSCANB) ? part[t] : 0;
    ls[t] = v;
    __syncthreads();
    for (int o = 1; o < 256; o <<= 1) {
        int x = (t >= o) ? ls[t - o] : 0;
        __syncthreads();
        ls[t] += x;
        __syncthreads();
    }
    if (t < NSCANB) part[t] = ls[t] - v;  // exclusive
}

__global__ __launch_bounds__(256) void k_offs(const int* __restrict__ counts,
                                              const int* __restrict__ part,
                                              int* __restrict__ offs) {
    __shared__ int ls[256];
    int t = threadIdx.x, i = blockIdx.x * 256 + t;
    int v = (i < NNODES) ? counts[i] : 0;
    ls[t] = v;
    __syncthreads();
    for (int o = 1; o < 256; o <<= 1) {
        int x = (t >= o) ? ls[t - o] : 0;
        __syncthreads();
        ls[t] += x;
        __syncthreads();
    }
    int excl = part[blockIdx.x] + ls[t] - v;
    if (i < NNODES) offs[i] = excl;
    if (i == NNODES - 1) offs[NNODES] = excl + v;
}

__global__ void k_scatter(const int* __restrict__ row, const int* __restrict__ col,
                          const int* __restrict__ offs, int* __restrict__ cursor,
                          const float* __restrict__ dinv, int2* __restrict__ csr) {
    int e = blockIdx.x * 256 + threadIdx.x;
    if (e < NEDGES) {
        int c = col[e], r = row[e];
        int pos = offs[c] + atomicAdd(&cursor[c], 1);
        float w = dinv[r] * dinv[c];
        csr[pos] = make_int2(r, __builtin_bit_cast(int, w));
    }
}

// ---------------- folded + MFMA-fragment-packed layer weights ----------------
__global__ void k_wcp(const float* __restrict__ w1, const float* __restrict__ w2,
                      unsigned short* __restrict__ Wp) {
    int idx = blockIdx.x * 256 + threadIdx.x;  // 8*32768
    if (idx >= NLAYERS * 32768) return;
    int i = idx >> 15;
    int rem = idx & 32767;
    int s = rem >> 12;
    int t = (rem >> 9) & 7;
    int lane = (rem >> 3) & 63;
    int j = rem & 7;
    int k = s * 32 + (lane >> 4) * 8 + j;
    int n = t * 16 + (lane & 15);
    float beta = logf(1.0f / (float)(i + 1) + 1.0f);
    float v;
    if (k < 128) {
        v = beta * w1[(i * 128 + k) * 128 + n] + ((k == n) ? (1.0f - beta) : 0.0f);
    } else {
        int k2 = k - 128;
        v = 0.5f * (beta * w2[(i * 128 + k2) * 128 + n] + ((k2 == n) ? (1.0f - beta) : 0.0f));
    }
    Wp[idx] = f2b(v);
}

// ---------------- lin1 (MFMA, fp32 x split hi/lo): h0 -> abuf[:,128:256) bf16 ----------------
__global__ __launch_bounds__(256) void k_lin1m(const float* __restrict__ x,
                                               const float* __restrict__ W,
                                               const float* __restrict__ b,
                                               unsigned short* __restrict__ abuf) {
    __shared__ __attribute__((aligned(16))) unsigned short Bs[8192];  // 16 KB
    int t = threadIdx.x;
    // pack W(64x128) into fragment layout: [(s*8+tt)*512 + lane*8 + j]
    for (int idx = t; idx < 8192; idx += 256) {
        int s = idx >> 12;          // 0..1
        int tt = (idx >> 9) & 7;    // 0..7
        int lane = (idx >> 3) & 63;
        int j = idx & 7;
        int k = s * 32 + (lane >> 4) * 8 + j;
        int n = tt * 16 + (lane & 15);
        Bs[idx] = f2b(W[k * 128 + n]);
    }
    __syncthreads();

    int w = t >> 6, lane = t & 63;
    int q = lane >> 4, r = lane & 15;
    int m0 = blockIdx.x * 64 + w * 16;
    int mA = m0 + r; if (mA > NNODES - 1) mA = NNODES - 1;
    const float* xrow = x + (size_t)mA * 64;

    f32x4 acc[8];
    float bn = b[((t & 15)) + 0];  // placeholder; real init below
#pragma unroll
    for (int tt = 0; tt < 8; ++tt) {
        float bv = b[tt * 16 + r];
        acc[tt] = (f32x4){bv, bv, bv, bv};
    }
    (void)bn;

#pragma unroll
    for (int s = 0; s < 2; ++s) {
        float xv[8];
        *(float4*)&xv[0] = *(const float4*)(xrow + s * 32 + q * 8);
        *(float4*)&xv[4] = *(const float4*)(xrow + s * 32 + q * 8 + 4);
        bhalf8 ah, al;
#pragma unroll
        for (int j = 0; j < 8; ++j) {
            unsigned short hb = f2b(xv[j]);
            ah[j] = (short)hb;
            al[j] = (short)f2b(xv[j] - b2f(hb));
        }
#pragma unroll
        for (int tt = 0; tt < 8; ++tt) {
            bhalf8 bf = *(const bhalf8*)&Bs[((s * 8 + tt) << 9) + lane * 8];
            acc[tt] = __builtin_amdgcn_mfma_f32_16x16x32_bf16(ah, bf, acc[tt], 0, 0, 0);
            acc[tt] = __builtin_amdgcn_mfma_f32_16x16x32_bf16(al, bf, acc[tt], 0, 0, 0);
        }
    }
#pragma unroll
    for (int i = 0; i < 4; ++i) {
        int mm = m0 + q * 4 + i;
        if (mm < NNODES) {
#pragma unroll
            for (int tt = 0; tt < 8; ++tt)
                abuf[(size_t)mm * 256 + 128 + tt * 16 + r] = f2b(acc[tt][i]);
        }
    }
}

// ---------------- SpMM with fused LayerNorm+ReLU of the source ----------------
template <int LN>
static __device__ __forceinline__ void acc_edge(unsigned a, float we, float s0, float c0,
                                                float s1, float c1,
                                                float& acc0, float& acc1) {
    float p0 = fmaf(b2f_lo(a), s0, c0);
    float p1 = fmaf(b2f_hi(a), s1, c1);
    if (LN) { p0 = fmaxf(p0, 0.0f); p1 = fmaxf(p1, 0.0f); }
    acc0 = fmaf(we, p0, acc0);
    acc1 = fmaf(we, p1, acc1);
}

template <int LN>
__global__ __launch_bounds__(256) void k_spmm4(const unsigned short* __restrict__ src,
                                               int stride,
                                               const float* __restrict__ stats,
                                               const float* __restrict__ nw,
                                               const float* __restrict__ nb,
                                               const int* __restrict__ offs,
                                               const int2* __restrict__ csr,
                                               const float* __restrict__ dinv,
                                               unsigned short* __restrict__ abuf) {
    int wid = (blockIdx.x * 256 + threadIdx.x) >> 6;
    int lane = threadIdx.x & 63;
    if (wid >= NNODES) return;
    float s0 = 1.0f, c0 = 0.0f, s1 = 1.0f, c1 = 0.0f;
    if (LN) {
        const float M = (float)NNODES * 128.0f;
        float mean = stats[0] / M;
        float var = stats[1] / M - mean * mean;
        float inv = 1.0f / (sqrtf(fmaxf(var, 0.0f)) + 1e-5f);
        s0 = inv * nw[lane * 2];
        c0 = nb[lane * 2] - mean * s0;
        s1 = inv * nw[lane * 2 + 1];
        c1 = nb[lane * 2 + 1] - mean * s1;
    }
    int c = wid;
    float di = dinv[c];
    float dw = di * di;
    unsigned hv = *(const unsigned*)(src + (size_t)c * stride + lane * 2);
    float v0 = fmaf(b2f_lo(hv), s0, c0), v1 = fmaf(b2f_hi(hv), s1, c1);
    if (LN) { v0 = fmaxf(v0, 0.0f); v1 = fmaxf(v1, 0.0f); }
    float acc0 = dw * v0, acc1 = dw * v1;
    int e = offs[c], e1 = offs[c + 1];
    for (; e + 8 <= e1; e += 8) {
        int2 E[8];
#pragma unroll
        for (int u = 0; u < 8; ++u) E[u] = csr[e + u];
        unsigned a[8];
#pragma unroll
        for (int u = 0; u < 8; ++u)
            a[u] = *(const unsigned*)(src + (size_t)E[u].x * stride + lane * 2);
#pragma unroll
        for (int u = 0; u < 8; ++u)
            acc_edge<LN>(a[u], __builtin_bit_cast(float, E[u].y), s0, c0, s1, c1, acc0, acc1);
    }
    if (e + 4 <= e1) {
        int2 E[4];
#pragma unroll
        for (int u = 0; u < 4; ++u) E[u] = csr[e + u];
        unsigned a[4];
#pragma unroll
        for (int u = 0; u < 4; ++u)
            a[u] = *(const unsigned*)(src + (size_t)E[u].x * stride + lane * 2);
#pragma unroll
        for (int u = 0; u < 4; ++u)
            acc_edge<LN>(a[u], __builtin_bit_cast(float, E[u].y), s0, c0, s1, c1, acc0, acc1);
        e += 4;
    }
    for (; e < e1; ++e) {
        int2 E0 = csr[e];
        unsigned a0 = *(const unsigned*)(src + (size_t)E0.x * stride + lane * 2);
        acc_edge<LN>(a0, __builtin_bit_cast(float, E0.y), s0, c0, s1, c1, acc0, acc1);
    }
    unsigned out = (unsigned)f2b(0.5f * acc0) | ((unsigned)f2b(0.5f * acc1) << 16);
    *(unsigned*)(abuf + (size_t)c * 256 + lane * 2) = out;
}

// ---------------- layer GEMM (MFMA): outb = abuf(50000x256 bf16) @ Wc + stats ----------------
__global__ __launch_bounds__(256) void k_gemm2(const unsigned short* __restrict__ A,
                                               const unsigned short* __restrict__ Bp,
                                               unsigned short* __restrict__ outb,
                                               float* __restrict__ stats) {
    __shared__ __attribute__((aligned(16))) unsigned short Bs[32768];  // 64 KB
    int t = threadIdx.x;
#pragma unroll
    for (int it = 0; it < 16; ++it) {
        int o = it * 2048 + t * 8;
        *(bhalf8*)&Bs[o] = *(const bhalf8*)&Bp[o];
    }
    __syncthreads();

    int w = t >> 6, lane = t & 63;
    int q = lane >> 4, r = lane & 15;
    float ps1 = 0.f, ps2 = 0.f;

#pragma unroll 1
    for (int sub = 0; sub < 2; ++sub) {
        int m0 = blockIdx.x * 128 + sub * 64 + w * 16;
        int mA = m0 + r; if (mA > NNODES - 1) mA = NNODES - 1;
        const unsigned short* arow = A + (size_t)mA * 256;

        f32x4 acc[8];
#pragma unroll
        for (int i = 0; i < 8; ++i) acc[i] = (f32x4){0.f, 0.f, 0.f, 0.f};

        bhalf8 afr[8];
#pragma unroll
        for (int s = 0; s < 8; ++s)
            afr[s] = *(const bhalf8*)(arow + s * 32 + q * 8);
#pragma unroll
        for (int s = 0; s < 8; ++s) {
#pragma unroll
            for (int nt = 0; nt < 8; ++nt) {
                bhalf8 bfr = *(const bhalf8*)&Bs[((s * 8 + nt) << 9) + lane * 8];
                acc[nt] = __builtin_amdgcn_mfma_f32_16x16x32_bf16(afr[s], bfr, acc[nt], 0, 0, 0);
            }
        }
#pragma unroll
        for (int i = 0; i < 4; ++i) {
            int mm = m0 + q * 4 + i;
            if (mm < NNODES) {
#pragma unroll
                for (int nt = 0; nt < 8; ++nt) {
                    float v = acc[nt][i];
                    ps1 += v; ps2 += v * v;
                    outb[(size_t)mm * 128 + nt * 16 + r] = f2b(v);
                }
            }
        }
    }
    __syncthreads();
    float* red = (float*)Bs;
    red[t] = ps1; red[256 + t] = ps2;
    __syncthreads();
    for (int o = 128; o > 0; o >>= 1) {
        if (t < o) { red[t] += red[t + o]; red[256 + t] += red[256 + t + o]; }
        __syncthreads();
    }
    if (t == 0) {
        atomicAdd(stats, red[0]);
        atomicAdd(stats + 1, red[256]);
    }
}

// ---------------- lin2 (MFMA) with fused final LayerNorm+ReLU ----------------
__global__ __launch_bounds__(256) void k_lin2m(const unsigned short* __restrict__ hsrc,
                                               const float* __restrict__ stats,
                                               const float* __restrict__ nw,
                                               const float* __restrict__ nb,
                                               const float* __restrict__ W,
                                               const float* __restrict__ b,
                                               float* __restrict__ out) {
    __shared__ __attribute__((aligned(16))) unsigned short Bs[8192];  // 16 KB
    __shared__ float lsk[128], lck[128];
    int t = threadIdx.x;
    const float M = (float)NNODES * 128.0f;
    float mean = stats[0] / M;
    float var = stats[1] / M - mean * mean;
    float inv = 1.0f / (sqrtf(fmaxf(var, 0.0f)) + 1e-5f);
    // pack W(128x64) into fragment layout: [(s*4+tt)*512 + lane*8 + j]
    for (int idx = t; idx < 8192; idx += 256) {
        int s = idx >> 11;          // 0..3
        int tt = (idx >> 9) & 3;    // 0..3
        int lane = (idx >> 3) & 63;
        int j = idx & 7;
        int k = s * 32 + (lane >> 4) * 8 + j;
        int n = tt * 16 + (lane & 15);
        Bs[idx] = f2b(W[k * 64 + n]);
    }
    if (t < 128) {
        float sk = inv * nw[t];
        lsk[t] = sk;
        lck[t] = nb[t] - mean * sk;
    }
    __syncthreads();

    int w = t >> 6, lane = t & 63;
    int q = lane >> 4, r = lane & 15;
    int m0 = blockIdx.x * 64 + w * 16;
    int mA = m0 + r; if (mA > NNODES - 1) mA = NNODES - 1;
    const unsigned short* arow = hsrc + (size_t)mA * 128;

    f32x4 acc[4];
#pragma unroll
    for (int tt = 0; tt < 4; ++tt) {
        float bv = b[tt * 16 + r];
        acc[tt] = (f32x4){bv, bv, bv, bv};
    }
#pragma unroll
    for (int s = 0; s < 4; ++s) {
        bhalf8 raw = *(const bhalf8*)(arow + s * 32 + q * 8);
        bhalf8 af;
#pragma unroll
        for (int j = 0; j < 8; ++j) {
            int k = s * 32 + q * 8 + j;
            float v = b2f((unsigned short)raw[j]);
            v = fmaxf(fmaf(v, lsk[k], lck[k]), 0.0f);
            af[j] = (short)f2b(v);
        }
#pragma unroll
        for (int tt = 0; tt < 4; ++tt) {
            bhalf8 bf = *(const bhalf8*)&Bs[((s * 4 + tt) << 9) + lane * 8];
            acc[tt] = __builtin_amdgcn_mfma_f32_16x16x32_bf16(af, bf, acc[tt], 0, 0, 0);
        }
    }
#pragma unroll
    for (int i = 0; i < 4; ++i) {
        int mm = m0 + q * 4 + i;
        if (mm < NNODES) {
#pragma unroll
            for (int tt = 0; tt < 4; ++tt)
                out[(size_t)mm * 64 + tt * 16 + r] = acc[tt][i];
        }
    }
}

// ---------------- launch ----------------

extern "C" void kernel_launch(void* const* d_in, const int* in_sizes, int n_in,
                              void* d_out, int out_size, void* d_ws, size_t ws_size,
                              hipStream_t stream) {
    const float* x      = (const float*)d_in[0];
    const int*   ei     = (const int*)d_in[1];
    const float* lin1_w = (const float*)d_in[2];
    const float* lin1_b = (const float*)d_in[3];
    const float* w1     = (const float*)d_in[4];
    const float* w2     = (const float*)d_in[5];
    const float* norm_w = (const float*)d_in[6];
    const float* norm_b = (const float*)d_in[7];
    const float* lin2_w = (const float*)d_in[8];
    const float* lin2_b = (const float*)d_in[9];
    float* out = (float*)d_out;

    const int* row = ei;
    const int* col = ei + NEDGES;

    char* p = (char*)d_ws;
    auto take = [&](size_t bytes) -> char* {
        char* r = p;
        p += (bytes + 255) & ~(size_t)255;
        return r;
    };
    unsigned short* abuf = (unsigned short*)take((size_t)NNODES * 256 * 2);
    unsigned short* outb = (unsigned short*)take((size_t)NNODES * 128 * 2);
    unsigned short* Wp   = (unsigned short*)take((size_t)NLAYERS * 32768 * 2);
    float* dinv    = (float*)take((size_t)NNODES * 4);
    int*   counts  = (int*)take((size_t)NNODES * 4);
    int*   cursor  = (int*)take((size_t)NNODES * 4);
    int*   offs    = (int*)take((size_t)(NNODES + 1) * 4);
    int*   part    = (int*)take((size_t)NSCANB * 4);
    int2*  csr     = (int2*)take((size_t)NEDGES * 8);
    float* stats   = (float*)take(64);

    hipMemsetAsync(counts, 0, (size_t)NNODES * 4, stream);
    hipMemsetAsync(cursor, 0, (size_t)NNODES * 4, stream);
    hipMemsetAsync(stats, 0, 64, stream);

    k_count<<<(NEDGES + 255) / 256, 256, 0, stream>>>(col, counts);
    k_dinv<<<(NNODES + 255) / 256, 256, 0, stream>>>(counts, dinv);
    k_bsum<<<NSCANB, 256, 0, stream>>>(counts, part);
    k_pscan<<<1, 256, 0, stream>>>(part);
    k_offs<<<NSCANB, 256, 0, stream>>>(counts, part, offs);
    k_scatter<<<(NEDGES + 255) / 256, 256, 0, stream>>>(row, col, offs, cursor, dinv, csr);
    k_wcp<<<(NLAYERS * 32768 + 255) / 256, 256, 0, stream>>>(w1, w2, Wp);
    k_lin1m<<<(NNODES + 63) / 64, 256, 0, stream>>>(x, lin1_w, lin1_b, abuf);

    for (int i = 0; i < NLAYERS; ++i) {
        if (i == 0) {
            k_spmm4<0><<<(NNODES * 64 + 255) / 256, 256, 0, stream>>>(
                abuf + 128, 256, stats, norm_w, norm_b, offs, csr, dinv, abuf);
        } else {
            k_spmm4<1><<<(NNODES * 64 + 255) / 256, 256, 0, stream>>>(
                outb, 128, stats + 2 * (i - 1), norm_w + (size_t)(i - 1) * 128,
                norm_b + (size_t)(i - 1) * 128, offs, csr, dinv, abuf);
        }
        k_gemm2<<<(NNODES + 127) / 128, 256, 0, stream>>>(abuf, Wp + (size_t)i * 32768,
                                                          outb, stats + 2 * i);
    }
    k_lin2m<<<(NNODES + 63) / 64, 256, 0, stream>>>(outb, stats + 14,
                                                    norm_w + 7 * 128, norm_b + 7 * 128,
                                                    lin2_w, lin2_b, out);
}

// Round 5
// 598.018 us; speedup vs baseline: 2.3507x; 1.0155x over previous
//
#include <hip/hip_runtime.h>
#include <hip/hip_bf16.h>
#include <math.h>

#define NNODES 50000
#define NEDGES 500000
#define NLAYERS 8
#define NSCANB 196  // ceil(NNODES/256)

typedef __attribute__((ext_vector_type(8))) short bhalf8;
typedef __attribute__((ext_vector_type(4))) float f32x4;

// fp32 -> bf16 bits, round-to-nearest-even
static __device__ __forceinline__ unsigned short f2b(float v) {
    unsigned u = __builtin_bit_cast(unsigned, v);
    u += 0x7fffu + ((u >> 16) & 1u);
    return (unsigned short)(u >> 16);
}
static __device__ __forceinline__ float b2f(unsigned short w) {
    return __builtin_bit_cast(float, (unsigned)w << 16);
}
static __device__ __forceinline__ float b2f_lo(unsigned w) {
    return __builtin_bit_cast(float, w << 16);
}
static __device__ __forceinline__ float b2f_hi(unsigned w) {
    return __builtin_bit_cast(float, w & 0xffff0000u);
}

// ---------------- graph preprocessing ----------------

__global__ void k_count(const int* __restrict__ col, int* __restrict__ counts) {
    int e = blockIdx.x * 256 + threadIdx.x;
    if (e < NEDGES) atomicAdd(&counts[col[e]], 1);
}

__global__ void k_dinv(const int* __restrict__ counts, float* __restrict__ dinv) {
    int i = blockIdx.x * 256 + threadIdx.x;
    if (i < NNODES) dinv[i] = rsqrtf((float)(counts[i] + 1));  // +1 self loop
}

__global__ __launch_bounds__(256) void k_bsum(const int* __restrict__ counts,
                                              int* __restrict__ part) {
    __shared__ int ls[256];
    int t = threadIdx.x, i = blockIdx.x * 256 + t;
    ls[t] = (i < NNODES) ? counts[i] : 0;
    __syncthreads();
    for (int o = 128; o > 0; o >>= 1) {
        if (t < o) ls[t] += ls[t + o];
        __syncthreads();
    }
    if (t == 0) part[blockIdx.x] = ls[0];
}

__global__ __launch_bounds__(256) void k_pscan(int* __restrict__ part) {
    __shared__ int ls[256];
    int t = threadIdx.x;
    int v = (t < NSCANB) ? part[t] : 0;
    ls[t] = v;
    __syncthreads();
    for (int o = 1; o < 256; o <<= 1) {
        int x = (t >= o) ? ls[t - o] : 0;
        __syncthreads();
        ls[t] += x;
        __syncthreads();
    }
    if (t < NSCANB) part[t] = ls[t] - v;  // exclusive
}

__global__ __launch_bounds__(256) void k_offs(const int* __restrict__ counts,
                                              const int* __restrict__ part,
                                              int* __restrict__ offs) {
    __shared__ int ls[256];
    int t = threadIdx.x, i = blockIdx.x * 256 + t;
    int v = (i < NNODES) ? counts[i] : 0;
    ls[t] = v;
    __syncthreads();
    for (int o = 1; o < 256; o <<= 1) {
        int x = (t >= o) ? ls[t - o] : 0;
        __syncthreads();
        ls[t] += x;
        __syncthreads();
    }
    int excl = part[blockIdx.x] + ls[t] - v;
    if (i < NNODES) offs[i] = excl;
    if (i == NNODES - 1) offs[NNODES] = excl + v;
}

__global__ void k_scatter(const int* __restrict__ row, const int* __restrict__ col,
                          const int* __restrict__ offs, int* __restrict__ cursor,
                          const float* __restrict__ dinv, int2* __restrict__ csr) {
    int e = blockIdx.x * 256 + threadIdx.x;
    if (e < NEDGES) {
        int c = col[e], r = row[e];
        int pos = offs[c] + atomicAdd(&cursor[c], 1);
        float w = dinv[r] * dinv[c];
        csr[pos] = make_int2(r, __builtin_bit_cast(int, w));
    }
}

// ---------------- folded + MFMA-fragment-packed layer weights ----------------
__global__ void k_wcp(const float* __restrict__ w1, const float* __restrict__ w2,
                      unsigned short* __restrict__ Wp) {
    int idx = blockIdx.x * 256 + threadIdx.x;  // 8*32768
    if (idx >= NLAYERS * 32768) return;
    int i = idx >> 15;
    int rem = idx & 32767;
    int s = rem >> 12;
    int t = (rem >> 9) & 7;
    int lane = (rem >> 3) & 63;
    int j = rem & 7;
    int k = s * 32 + (lane >> 4) * 8 + j;
    int n = t * 16 + (lane & 15);
    float beta = logf(1.0f / (float)(i + 1) + 1.0f);
    float v;
    if (k < 128) {
        v = beta * w1[(i * 128 + k) * 128 + n] + ((k == n) ? (1.0f - beta) : 0.0f);
    } else {
        int k2 = k - 128;
        v = 0.5f * (beta * w2[(i * 128 + k2) * 128 + n] + ((k2 == n) ? (1.0f - beta) : 0.0f));
    }
    Wp[idx] = f2b(v);
}

// ---------------- lin1 (MFMA, fp32 x split hi/lo): h0 -> abuf[:,128:256) bf16 ----------------
__global__ __launch_bounds__(256) void k_lin1m(const float* __restrict__ x,
                                               const float* __restrict__ W,
                                               const float* __restrict__ b,
                                               unsigned short* __restrict__ abuf) {
    __shared__ __attribute__((aligned(16))) unsigned short Bs[8192];  // 16 KB
    int t = threadIdx.x;
    for (int idx = t; idx < 8192; idx += 256) {
        int s = idx >> 12;          // 0..1
        int tt = (idx >> 9) & 7;    // 0..7
        int lane = (idx >> 3) & 63;
        int j = idx & 7;
        int k = s * 32 + (lane >> 4) * 8 + j;
        int n = tt * 16 + (lane & 15);
        Bs[idx] = f2b(W[k * 128 + n]);
    }
    __syncthreads();

    int w = t >> 6, lane = t & 63;
    int q = lane >> 4, r = lane & 15;
    int m0 = blockIdx.x * 64 + w * 16;
    int mA = m0 + r; if (mA > NNODES - 1) mA = NNODES - 1;
    const float* xrow = x + (size_t)mA * 64;

    f32x4 acc[8];
#pragma unroll
    for (int tt = 0; tt < 8; ++tt) {
        float bv = b[tt * 16 + r];
        acc[tt] = (f32x4){bv, bv, bv, bv};
    }

#pragma unroll
    for (int s = 0; s < 2; ++s) {
        float xv[8];
        *(float4*)&xv[0] = *(const float4*)(xrow + s * 32 + q * 8);
        *(float4*)&xv[4] = *(const float4*)(xrow + s * 32 + q * 8 + 4);
        bhalf8 ah, al;
#pragma unroll
        for (int j = 0; j < 8; ++j) {
            unsigned short hb = f2b(xv[j]);
            ah[j] = (short)hb;
            al[j] = (short)f2b(xv[j] - b2f(hb));
        }
#pragma unroll
        for (int tt = 0; tt < 8; ++tt) {
            bhalf8 bf = *(const bhalf8*)&Bs[((s * 8 + tt) << 9) + lane * 8];
            acc[tt] = __builtin_amdgcn_mfma_f32_16x16x32_bf16(ah, bf, acc[tt], 0, 0, 0);
            acc[tt] = __builtin_amdgcn_mfma_f32_16x16x32_bf16(al, bf, acc[tt], 0, 0, 0);
        }
    }
#pragma unroll
    for (int i = 0; i < 4; ++i) {
        int mm = m0 + q * 4 + i;
        if (mm < NNODES) {
#pragma unroll
            for (int tt = 0; tt < 8; ++tt)
                abuf[(size_t)mm * 256 + 128 + tt * 16 + r] = f2b(acc[tt][i]);
        }
    }
}

// ---------------- SpMM: half-wave per node, 4 dims/lane, masked 8-groups ----------------
template <int LN>
__global__ __launch_bounds__(256) void k_spmm5(const unsigned short* __restrict__ src,
                                               int stride,
                                               const float* __restrict__ stats,
                                               const float* __restrict__ nw,
                                               const float* __restrict__ nb,
                                               const int* __restrict__ offs,
                                               const int2* __restrict__ csr,
                                               const float* __restrict__ dinv,
                                               unsigned short* __restrict__ abuf) {
    int gt = blockIdx.x * 256 + threadIdx.x;
    int c = gt >> 5;          // node (2 nodes per wave)
    int s = threadIdx.x & 31; // sub-lane: dims [4s, 4s+4)
    if (c >= NNODES) return;
    float s0 = 1.0f, c0 = 0.0f, s1 = 1.0f, c1 = 0.0f, s2 = 1.0f, c2 = 0.0f, s3 = 1.0f, c3 = 0.0f;
    if (LN) {
        const float M = (float)NNODES * 128.0f;
        float mean = stats[0] / M;
        float var = stats[1] / M - mean * mean;
        float inv = 1.0f / (sqrtf(fmaxf(var, 0.0f)) + 1e-5f);
        float4 w4 = *(const float4*)&nw[s * 4];
        float4 b4 = *(const float4*)&nb[s * 4];
        s0 = inv * w4.x; c0 = b4.x - mean * s0;
        s1 = inv * w4.y; c1 = b4.y - mean * s1;
        s2 = inv * w4.z; c2 = b4.z - mean * s2;
        s3 = inv * w4.w; c3 = b4.w - mean * s3;
    }
    int e0 = offs[c], e1 = offs[c + 1];
    float di = dinv[c];
    float dw = di * di;
    uint2 hv = *(const uint2*)(src + (size_t)c * stride + s * 4);
    float v0 = fmaf(b2f_lo(hv.x), s0, c0), v1 = fmaf(b2f_hi(hv.x), s1, c1);
    float v2 = fmaf(b2f_lo(hv.y), s2, c2), v3 = fmaf(b2f_hi(hv.y), s3, c3);
    if (LN) {
        v0 = fmaxf(v0, 0.0f); v1 = fmaxf(v1, 0.0f);
        v2 = fmaxf(v2, 0.0f); v3 = fmaxf(v3, 0.0f);
    }
    float acc0 = dw * v0, acc1 = dw * v1, acc2 = dw * v2, acc3 = dw * v3;

    for (int e = e0; e < e1; e += 8) {
        int2 E[8];
        float wg[8];
#pragma unroll
        for (int u = 0; u < 8; ++u) {
            int ee = e + u;
            bool valid = ee < e1;
            E[u] = csr[valid ? ee : (e1 - 1)];
            wg[u] = valid ? __builtin_bit_cast(float, E[u].y) : 0.0f;
        }
        uint2 a[8];
#pragma unroll
        for (int u = 0; u < 8; ++u)
            a[u] = *(const uint2*)(src + (size_t)E[u].x * stride + s * 4);
#pragma unroll
        for (int u = 0; u < 8; ++u) {
            float p0 = fmaf(b2f_lo(a[u].x), s0, c0);
            float p1 = fmaf(b2f_hi(a[u].x), s1, c1);
            float p2 = fmaf(b2f_lo(a[u].y), s2, c2);
            float p3 = fmaf(b2f_hi(a[u].y), s3, c3);
            if (LN) {
                p0 = fmaxf(p0, 0.0f); p1 = fmaxf(p1, 0.0f);
                p2 = fmaxf(p2, 0.0f); p3 = fmaxf(p3, 0.0f);
            }
            acc0 = fmaf(wg[u], p0, acc0);
            acc1 = fmaf(wg[u], p1, acc1);
            acc2 = fmaf(wg[u], p2, acc2);
            acc3 = fmaf(wg[u], p3, acc3);
        }
    }
    uint2 outv;
    outv.x = (unsigned)f2b(0.5f * acc0) | ((unsigned)f2b(0.5f * acc1) << 16);
    outv.y = (unsigned)f2b(0.5f * acc2) | ((unsigned)f2b(0.5f * acc3) << 16);
    *(uint2*)(abuf + (size_t)c * 256 + s * 4) = outv;
}

// ---------------- layer GEMM (MFMA): outb = abuf(50000x256 bf16) @ Wc + stats ----------------
__global__ __launch_bounds__(256) void k_gemm2(const unsigned short* __restrict__ A,
                                               const unsigned short* __restrict__ Bp,
                                               unsigned short* __restrict__ outb,
                                               float* __restrict__ stats) {
    __shared__ __attribute__((aligned(16))) unsigned short Bs[32768];  // 64 KB
    int t = threadIdx.x;
#pragma unroll
    for (int it = 0; it < 16; ++it) {
        int o = it * 2048 + t * 8;
        *(bhalf8*)&Bs[o] = *(const bhalf8*)&Bp[o];
    }
    __syncthreads();

    int w = t >> 6, lane = t & 63;
    int q = lane >> 4, r = lane & 15;
    float ps1 = 0.f, ps2 = 0.f;

#pragma unroll 1
    for (int sub = 0; sub < 2; ++sub) {
        int m0 = blockIdx.x * 128 + sub * 64 + w * 16;
        int mA = m0 + r; if (mA > NNODES - 1) mA = NNODES - 1;
        const unsigned short* arow = A + (size_t)mA * 256;

        f32x4 acc[8];
#pragma unroll
        for (int i = 0; i < 8; ++i) acc[i] = (f32x4){0.f, 0.f, 0.f, 0.f};

        bhalf8 afr[8];
#pragma unroll
        for (int s = 0; s < 8; ++s)
            afr[s] = *(const bhalf8*)(arow + s * 32 + q * 8);
#pragma unroll
        for (int s = 0; s < 8; ++s) {
#pragma unroll
            for (int nt = 0; nt < 8; ++nt) {
                bhalf8 bfr = *(const bhalf8*)&Bs[((s * 8 + nt) << 9) + lane * 8];
                acc[nt] = __builtin_amdgcn_mfma_f32_16x16x32_bf16(afr[s], bfr, acc[nt], 0, 0, 0);
            }
        }
#pragma unroll
        for (int i = 0; i < 4; ++i) {
            int mm = m0 + q * 4 + i;
            if (mm < NNODES) {
#pragma unroll
                for (int nt = 0; nt < 8; ++nt) {
                    float v = acc[nt][i];
                    ps1 += v; ps2 += v * v;
                    outb[(size_t)mm * 128 + nt * 16 + r] = f2b(v);
                }
            }
        }
    }
    __syncthreads();
    float* red = (float*)Bs;
    red[t] = ps1; red[256 + t] = ps2;
    __syncthreads();
    for (int o = 128; o > 0; o >>= 1) {
        if (t < o) { red[t] += red[t + o]; red[256 + t] += red[256 + t + o]; }
        __syncthreads();
    }
    if (t == 0) {
        atomicAdd(stats, red[0]);
        atomicAdd(stats + 1, red[256]);
    }
}

// ---------------- lin2 (MFMA) with fused final LayerNorm+ReLU ----------------
__global__ __launch_bounds__(256) void k_lin2m(const unsigned short* __restrict__ hsrc,
                                               const float* __restrict__ stats,
                                               const float* __restrict__ nw,
                                               const float* __restrict__ nb,
                                               const float* __restrict__ W,
                                               const float* __restrict__ b,
                                               float* __restrict__ out) {
    __shared__ __attribute__((aligned(16))) unsigned short Bs[8192];  // 16 KB
    __shared__ float lsk[128], lck[128];
    int t = threadIdx.x;
    const float M = (float)NNODES * 128.0f;
    float mean = stats[0] / M;
    float var = stats[1] / M - mean * mean;
    float inv = 1.0f / (sqrtf(fmaxf(var, 0.0f)) + 1e-5f);
    for (int idx = t; idx < 8192; idx += 256) {
        int s = idx >> 11;          // 0..3
        int tt = (idx >> 9) & 3;    // 0..3
        int lane = (idx >> 3) & 63;
        int j = idx & 7;
        int k = s * 32 + (lane >> 4) * 8 + j;
        int n = tt * 16 + (lane & 15);
        Bs[idx] = f2b(W[k * 64 + n]);
    }
    if (t < 128) {
        float sk = inv * nw[t];
        lsk[t] = sk;
        lck[t] = nb[t] - mean * sk;
    }
    __syncthreads();

    int w = t >> 6, lane = t & 63;
    int q = lane >> 4, r = lane & 15;
    int m0 = blockIdx.x * 64 + w * 16;
    int mA = m0 + r; if (mA > NNODES - 1) mA = NNODES - 1;
    const unsigned short* arow = hsrc + (size_t)mA * 128;

    f32x4 acc[4];
#pragma unroll
    for (int tt = 0; tt < 4; ++tt) {
        float bv = b[tt * 16 + r];
        acc[tt] = (f32x4){bv, bv, bv, bv};
    }
#pragma unroll
    for (int s = 0; s < 4; ++s) {
        bhalf8 raw = *(const bhalf8*)(arow + s * 32 + q * 8);
        bhalf8 af;
#pragma unroll
        for (int j = 0; j < 8; ++j) {
            int k = s * 32 + q * 8 + j;
            float v = b2f((unsigned short)raw[j]);
            v = fmaxf(fmaf(v, lsk[k], lck[k]), 0.0f);
            af[j] = (short)f2b(v);
        }
#pragma unroll
        for (int tt = 0; tt < 4; ++tt) {
            bhalf8 bf = *(const bhalf8*)&Bs[((s * 4 + tt) << 9) + lane * 8];
            acc[tt] = __builtin_amdgcn_mfma_f32_16x16x32_bf16(af, bf, acc[tt], 0, 0, 0);
        }
    }
#pragma unroll
    for (int i = 0; i < 4; ++i) {
        int mm = m0 + q * 4 + i;
        if (mm < NNODES) {
#pragma unroll
            for (int tt = 0; tt < 4; ++tt)
                out[(size_t)mm * 64 + tt * 16 + r] = acc[tt][i];
        }
    }
}

// ---------------- launch ----------------

extern "C" void kernel_launch(void* const* d_in, const int* in_sizes, int n_in,
                              void* d_out, int out_size, void* d_ws, size_t ws_size,
                              hipStream_t stream) {
    const float* x      = (const float*)d_in[0];
    const int*   ei     = (const int*)d_in[1];
    const float* lin1_w = (const float*)d_in[2];
    const float* lin1_b = (const float*)d_in[3];
    const float* w1     = (const float*)d_in[4];
    const float* w2     = (const float*)d_in[5];
    const float* norm_w = (const float*)d_in[6];
    const float* norm_b = (const float*)d_in[7];
    const float* lin2_w = (const float*)d_in[8];
    const float* lin2_b = (const float*)d_in[9];
    float* out = (float*)d_out;

    const int* row = ei;
    const int* col = ei + NEDGES;

    char* p = (char*)d_ws;
    auto take = [&](size_t bytes) -> char* {
        char* r = p;
        p += (bytes + 255) & ~(size_t)255;
        return r;
    };
    unsigned short* abuf = (unsigned short*)take((size_t)NNODES * 256 * 2);
    unsigned short* outb = (unsigned short*)take((size_t)NNODES * 128 * 2);
    unsigned short* Wp   = (unsigned short*)take((size_t)NLAYERS * 32768 * 2);
    float* dinv    = (float*)take((size_t)NNODES * 4);
    int*   counts  = (int*)take((size_t)NNODES * 4);
    int*   cursor  = (int*)take((size_t)NNODES * 4);
    int*   offs    = (int*)take((size_t)(NNODES + 1) * 4);
    int*   part    = (int*)take((size_t)NSCANB * 4);
    int2*  csr     = (int2*)take((size_t)NEDGES * 8);
    float* stats   = (float*)take(64);

    hipMemsetAsync(counts, 0, (size_t)NNODES * 4, stream);
    hipMemsetAsync(cursor, 0, (size_t)NNODES * 4, stream);
    hipMemsetAsync(stats, 0, 64, stream);

    k_count<<<(NEDGES + 255) / 256, 256, 0, stream>>>(col, counts);
    k_dinv<<<(NNODES + 255) / 256, 256, 0, stream>>>(counts, dinv);
    k_bsum<<<NSCANB, 256, 0, stream>>>(counts, part);
    k_pscan<<<1, 256, 0, stream>>>(part);
    k_offs<<<NSCANB, 256, 0, stream>>>(counts, part, offs);
    k_scatter<<<(NEDGES + 255) / 256, 256, 0, stream>>>(row, col, offs, cursor, dinv, csr);
    k_wcp<<<(NLAYERS * 32768 + 255) / 256, 256, 0, stream>>>(w1, w2, Wp);
    k_lin1m<<<(NNODES + 63) / 64, 256, 0, stream>>>(x, lin1_w, lin1_b, abuf);

    for (int i = 0; i < NLAYERS; ++i) {
        if (i == 0) {
            k_spmm5<0><<<(NNODES * 32 + 255) / 256, 256, 0, stream>>>(
                abuf + 128, 256, stats, norm_w, norm_b, offs, csr, dinv, abuf);
        } else {
            k_spmm5<1><<<(NNODES * 32 + 255) / 256, 256, 0, stream>>>(
                outb, 128, stats + 2 * (i - 1), norm_w + (size_t)(i - 1) * 128,
                norm_b + (size_t)(i - 1) * 128, offs, csr, dinv, abuf);
        }
        k_gemm2<<<(NNODES + 127) / 128, 256, 0, stream>>>(abuf, Wp + (size_t)i * 32768,
                                                          outb, stats + 2 * i);
    }
    k_lin2m<<<(NNODES + 63) / 64, 256, 0, stream>>>(outb, stats + 14,
                                                    norm_w + 7 * 128, norm_b + 7 * 128,
                                                    lin2_w, lin2_b, out);
}